// Round 4
// baseline (1027.479 us; speedup 1.0000x reference)
//
#include <hip/hip_runtime.h>

// ---------------------------------------------------------------------------
// FullMHA: x(32,512,2048) fp32, w_qkv(6144,2048), w_out(2048,2048)
// qkv = x @ w_qkv^T ; RoPE(64) on q,k ; causal softmax(QK^T/sqrt(128))V ;
// out = y @ w_out^T.  All GEMMs in bf16 MFMA (16x16x32), fp32 accumulate.
// R6 = R5 resubmit (round-3 bench died with "container failed twice", no
// profile; source audit found no OOB/race/hang - see journal).
// R5: attention rewritten (GEMMs frozen at R4):
//   - rope_apply pre-ropes+scales q and ropes k in-place in qkvb (once,
//     instead of per (qt,ktile) inside attn -> kills redundant trig/VALU).
//   - attn: Q frags in registers; K staged by global_load_lds with chunk-XOR
//     swizzle (no VALU staging); K/V^T double-buffered, next-tile loads
//     issued at top of iter, vmcnt(0) only after PV (latency hidden under
//     QK+softmax+PV); ONE barrier per iteration (was 3 syncthreads);
//     setprio around MFMA. LDS 73KB -> still 2 blocks/CU.
// ---------------------------------------------------------------------------

typedef __bf16 bf16x8 __attribute__((ext_vector_type(8)));
typedef float floatx4 __attribute__((ext_vector_type(4)));

__device__ __forceinline__ unsigned short f2bf(float f) {
  union { float f; unsigned u; } v; v.f = f;
  unsigned r = v.u + 0x7FFFu + ((v.u >> 16) & 1u);   // RNE
  return (unsigned short)(r >> 16);
}
__device__ __forceinline__ float bf2f(unsigned short h) {
  union { unsigned u; float f; } v; v.u = ((unsigned)h) << 16; return v.f;
}

__device__ __forceinline__ void load_lds16(const void* g, void* l) {
  __builtin_amdgcn_global_load_lds((__attribute__((address_space(1))) void*)g,
                                   (__attribute__((address_space(3))) void*)l,
                                   16, 0, 0);
}

#define BARRIER() asm volatile("s_barrier" ::: "memory")
#define VMCNT6()  asm volatile("s_waitcnt vmcnt(6)" ::: "memory")
#define VMCNT0()  asm volatile("s_waitcnt vmcnt(0)" ::: "memory")

// ---------------- RoPE tables ----------------------------------------------
__global__ void rope_tables(float* __restrict__ cost, float* __restrict__ sint) {
  int i = blockIdx.x * 256 + threadIdx.x;
  if (i >= 512 * 32) return;
  int t = i >> 5, f = i & 31;
  float e = -(float)(2 * f) / 64.0f;
  float freq = powf(10000.0f, e);
  float ang = (float)t * freq;
  cost[i] = cosf(ang);
  sint[i] = sinf(ang);
}

// ---------------- fp32 -> bf16 cast, 8 elems/thread ------------------------
__global__ void cast_bf16(const float* __restrict__ in,
                          unsigned short* __restrict__ out, int n8) {
  int i = blockIdx.x * 256 + threadIdx.x;
  if (i >= n8) return;
  float4 a = ((const float4*)in)[2 * i];
  float4 b = ((const float4*)in)[2 * i + 1];
  union { uint4 v; unsigned short u[8]; } o;
  o.u[0] = f2bf(a.x); o.u[1] = f2bf(a.y); o.u[2] = f2bf(a.z); o.u[3] = f2bf(a.w);
  o.u[4] = f2bf(b.x); o.u[5] = f2bf(b.y); o.u[6] = f2bf(b.z); o.u[7] = f2bf(b.w);
  ((uint4*)out)[i] = o.v;
}

// ---------------- RoPE applied in-place to q,k of qkvb ---------------------
// One thread per (token, head): rope+scale q[0:64], scale q[64:128],
// rope k[0:64]. Bit-identical to the math previously done inside attn.
__global__ __launch_bounds__(256) void rope_apply(
    unsigned short* __restrict__ qkv, const float* __restrict__ cost,
    const float* __restrict__ sint) {
  const int idx = blockIdx.x * 256 + threadIdx.x;   // 262144 total
  const int tok = idx >> 4, h = idx & 15;
  const int t = tok & 511;
  const float scale = 0.08838834764831845f * 1.4426950408889634f;
  unsigned short* qrow = qkv + (size_t)tok * 6144 + h * 128;
  unsigned short* krow = qrow + 2048;

  float cs[32], sn[32];
#pragma unroll
  for (int j = 0; j < 8; ++j) {
    *(float4*)&cs[j * 4] = *(const float4*)&cost[t * 32 + j * 4];
    *(float4*)&sn[j * 4] = *(const float4*)&sint[t * 32 + j * 4];
  }
  union u32x4 { uint4 v[4]; unsigned short u[32]; };
  u32x4 q1, q2, k1, k2, o1, o2, o3, o4;
#pragma unroll
  for (int j = 0; j < 4; ++j) {
    q1.v[j] = *(const uint4*)(qrow + j * 8);
    q2.v[j] = *(const uint4*)(qrow + 32 + j * 8);
    k1.v[j] = *(const uint4*)(krow + j * 8);
    k2.v[j] = *(const uint4*)(krow + 32 + j * 8);
  }
#pragma unroll
  for (int d = 0; d < 32; ++d) {
    float c = cs[d], s = sn[d];
    float qx1 = bf2f(q1.u[d]), qx2 = bf2f(q2.u[d]);
    o1.u[d] = f2bf((qx1 * c - qx2 * s) * scale);
    o2.u[d] = f2bf((qx2 * c + qx1 * s) * scale);
    float kx1 = bf2f(k1.u[d]), kx2 = bf2f(k2.u[d]);
    o3.u[d] = f2bf(kx1 * c - kx2 * s);
    o4.u[d] = f2bf(kx2 * c + kx1 * s);
  }
#pragma unroll
  for (int j = 0; j < 4; ++j) {
    *(uint4*)(qrow + j * 8)      = o1.v[j];
    *(uint4*)(qrow + 32 + j * 8) = o2.v[j];
    *(uint4*)(krow + j * 8)      = o3.v[j];
    *(uint4*)(krow + 32 + j * 8) = o4.v[j];
  }
#pragma unroll
  for (int j = 0; j < 8; ++j) {   // q pass-through dims * scale
    union { uint4 v; unsigned short u[8]; } p, po;
    p.v = *(const uint4*)(qrow + 64 + j * 8);
#pragma unroll
    for (int jj = 0; jj < 8; ++jj) po.u[jj] = f2bf(bf2f(p.u[jj]) * scale);
    *(uint4*)(qrow + 64 + j * 8) = po.v;
  }
}

// ---------------- GEMM: C[M,N] = A[M,K] * Bt[N,K]^T  (bf16, 256^2 8-wave) --
// (Frozen R4: 4 phases/K-tile, reads 12/8/4/0, vmcnt(6) per tile.)
template <int OUT_BF16>
__global__ __launch_bounds__(512, 2) void gemm256(
    const unsigned short* __restrict__ A, const unsigned short* __restrict__ Bt,
    void* __restrict__ Cout, int M, int N, int K) {
  __shared__ __align__(16) unsigned short As[2][16384];
  __shared__ __align__(16) unsigned short Bs[2][16384];

  const int tid = threadIdx.x;
  const int nbx = gridDim.x;
  const int nwg = nbx * gridDim.y;
  const int lin = blockIdx.y * nbx + blockIdx.x;
  const int swz = (lin & 7) * (nwg >> 3) + (lin >> 3);
  const int bm = swz / nbx, bn = swz % nbx;

  const int w = tid >> 6, l = tid & 63;
  const int wm = w >> 2, wn = w & 3;
  const int quad = l >> 4, cl = l & 15;
  const int xs0 = ((0 + quad) ^ (cl & 7)) << 3;
  const int xs1 = ((4 + quad) ^ (cl & 7)) << 3;
  const int aoff = (wm * 128 + cl) * 64;
  const int boff = (wn * 64 + cl) * 64;

  const int srow = tid >> 3;
  const int lc = (tid & 7) ^ (srow & 7);
  const unsigned short* Ag = A + (size_t)(bm * 256 + srow) * K + lc * 8;
  const unsigned short* Bg = Bt + (size_t)(bn * 256 + srow) * K + lc * 8;

  auto stageA = [&](int q, int h, int k0) {
    const unsigned short* src = Ag + (size_t)(h * 128) * K + k0;
    unsigned short* dst = &As[q][0] + h * 8192 + tid * 8;
    load_lds16(src, dst);
    load_lds16(src + (size_t)64 * K, dst + 4096);
  };
  auto stageB = [&](int q, int h, int k0) {
    const unsigned short* src = Bg + (size_t)(h * 128) * K + k0;
    unsigned short* dst = &Bs[q][0] + h * 8192 + tid * 8;
    load_lds16(src, dst);
    load_lds16(src + (size_t)64 * K, dst + 4096);
  };

  floatx4 acc[8][4] = {};
  const int NT = K >> 6;

  stageA(0, 0, 0);  stageA(0, 1, 0);  stageB(0, 0, 0);  stageB(0, 1, 0);
  stageA(1, 0, 64); stageA(1, 1, 64); stageB(1, 0, 64);
  VMCNT6();
  BARRIER();

  for (int t = 0; t < NT; ++t) {
    const int q = t & 1;
    const unsigned short* pA = &As[q][0] + aoff;
    const unsigned short* pB = &Bs[q][0] + boff;
    const int k2 = (t + 2) << 6;
    const bool s2 = (t + 2) < NT;

    bf16x8 a0[4][2], a1[4][2], b0[2][2], b1[2][2];
    // phase 1: (m0, n0)
#pragma unroll
    for (int mi = 0; mi < 4; ++mi) {
      a0[mi][0] = *(const bf16x8*)(pA + mi * 1024 + xs0);
      a0[mi][1] = *(const bf16x8*)(pA + mi * 1024 + xs1);
    }
#pragma unroll
    for (int ni = 0; ni < 2; ++ni) {
      b0[ni][0] = *(const bf16x8*)(pB + ni * 1024 + xs0);
      b0[ni][1] = *(const bf16x8*)(pB + ni * 1024 + xs1);
    }
    if (t + 1 < NT) stageB(q ^ 1, 1, (t + 1) << 6);
    BARRIER();
    __builtin_amdgcn_s_setprio(1);
#pragma unroll
    for (int mi = 0; mi < 4; ++mi)
#pragma unroll
      for (int ni = 0; ni < 2; ++ni)
#pragma unroll
        for (int ks = 0; ks < 2; ++ks)
          acc[mi][ni] = __builtin_amdgcn_mfma_f32_16x16x32_bf16(
              a0[mi][ks], b0[ni][ks], acc[mi][ni], 0, 0, 0);
    __builtin_amdgcn_s_setprio(0);
    BARRIER();
    // phase 2: (m1, n0)
#pragma unroll
    for (int mi = 0; mi < 4; ++mi) {
      a1[mi][0] = *(const bf16x8*)(pA + (mi + 4) * 1024 + xs0);
      a1[mi][1] = *(const bf16x8*)(pA + (mi + 4) * 1024 + xs1);
    }
    BARRIER();
    __builtin_amdgcn_s_setprio(1);
#pragma unroll
    for (int mi = 0; mi < 4; ++mi)
#pragma unroll
      for (int ni = 0; ni < 2; ++ni)
#pragma unroll
        for (int ks = 0; ks < 2; ++ks)
          acc[mi + 4][ni] = __builtin_amdgcn_mfma_f32_16x16x32_bf16(
              a1[mi][ks], b0[ni][ks], acc[mi + 4][ni], 0, 0, 0);
    __builtin_amdgcn_s_setprio(0);
    BARRIER();
    // phase 3: (m1, n1)
#pragma unroll
    for (int ni = 0; ni < 2; ++ni) {
      b1[ni][0] = *(const bf16x8*)(pB + (ni + 2) * 1024 + xs0);
      b1[ni][1] = *(const bf16x8*)(pB + (ni + 2) * 1024 + xs1);
    }
    if (s2) stageA(q, 0, k2);
    BARRIER();
    __builtin_amdgcn_s_setprio(1);
#pragma unroll
    for (int mi = 0; mi < 4; ++mi)
#pragma unroll
      for (int ni = 0; ni < 2; ++ni)
#pragma unroll
        for (int ks = 0; ks < 2; ++ks)
          acc[mi + 4][ni + 2] = __builtin_amdgcn_mfma_f32_16x16x32_bf16(
              a1[mi][ks], b1[ni][ks], acc[mi + 4][ni + 2], 0, 0, 0);
    __builtin_amdgcn_s_setprio(0);
    BARRIER();
    // phase 4: (m0, n1)
    if (s2) { stageA(q, 1, k2); stageB(q, 0, k2); }
    BARRIER();
    __builtin_amdgcn_s_setprio(1);
#pragma unroll
    for (int mi = 0; mi < 4; ++mi)
#pragma unroll
      for (int ni = 0; ni < 2; ++ni)
#pragma unroll
        for (int ks = 0; ks < 2; ++ks)
          acc[mi][ni + 2] = __builtin_amdgcn_mfma_f32_16x16x32_bf16(
              a0[mi][ks], b1[ni][ks], acc[mi][ni + 2], 0, 0, 0);
    __builtin_amdgcn_s_setprio(0);
    if (t < NT - 2) { VMCNT6(); } else { VMCNT0(); }
    BARRIER();
  }

#pragma unroll
  for (int mi = 0; mi < 8; ++mi)
#pragma unroll
    for (int ni = 0; ni < 4; ++ni)
#pragma unroll
      for (int r = 0; r < 4; ++r) {
        const int gm = bm * 256 + wm * 128 + mi * 16 + quad * 4 + r;
        const int gn = bn * 256 + wn * 64 + ni * 16 + cl;
        const float v = acc[mi][ni][r];
        if (OUT_BF16)
          ((unsigned short*)Cout)[(size_t)gm * N + gn] = f2bf(v);
        else
          ((float*)Cout)[(size_t)gm * N + gn] = v;
      }
}

// ---------------- Causal flash attention (q,k pre-roped/scaled) ------------
// grid (B*H=512, T/64=8), 256 threads = 4 waves, wave w owns q-rows w*16..+16.
// Q frags in registers. K double-buffered in LDS via global_load_lds with
// chunk-XOR swizzle; V^T double-buffered via reg-transpose. Next tile's
// loads issued at top of iter, vmcnt(0) only after PV. One barrier per iter.
__global__ __launch_bounds__(256) void attn_kernel(
    const unsigned short* __restrict__ qkv, unsigned short* __restrict__ y) {
  __shared__ __align__(16) unsigned short Ks[2][64][128];   // chunk-swizzled
  __shared__ __align__(16) unsigned short VTs[2][128][64];  // chunk-swizzled
  __shared__ __align__(16) unsigned short Ps[4][16][72];

  const int bh = blockIdx.x, qt = blockIdx.y;
  const int b = bh >> 4, h = bh & 15;
  const int tid = threadIdx.x, w = tid >> 6, l = tid & 63;
  const int quad = l >> 4, cl = l & 15;

  // ---- Q fragments -> registers (already roped & scaled) ----
  bf16x8 aq[4];
  {
    const unsigned short* qrow =
        qkv + (size_t)(b * 512 + qt * 64 + w * 16 + cl) * 6144 + h * 128 +
        quad * 8;
#pragma unroll
    for (int kc = 0; kc < 4; ++kc) aq[kc] = *(const bf16x8*)(qrow + kc * 32);
  }

  // ---- K staging map (global_load_lds, pre-swizzled source chunk) ----
  const int krow = tid >> 4;                    // slab-row 0..15
  const int kslot = tid & 15;                   // dest chunk slot
  const int kchunk = (kslot & 8) | ((kslot & 7) ^ (krow & 7));
  const unsigned short* kgbase =
      qkv + (size_t)(b * 512) * 6144 + 2048 + h * 128 + kchunk * 8;
  auto stageK = [&](int buf, int kt) {
#pragma unroll
    for (int slab = 0; slab < 4; ++slab) {
      const unsigned short* src =
          kgbase + (size_t)(kt * 64 + slab * 16 + krow) * 6144;
      load_lds16(src, &Ks[buf][0][0] + slab * 2048 + tid * 8);
    }
  };

  // ---- V staging: 8 kk-rows x 4 d-cols per thread, reg-transpose ----
  const int rowg = tid >> 5, colg = tid & 31;
  const unsigned short* vgbase =
      qkv + (size_t)(b * 512 + rowg * 8) * 6144 + 4096 + h * 128 + colg * 4;
  uint2 rv[8];
  auto loadV = [&](int kt) {
    const unsigned short* p = vgbase + (size_t)(kt * 64) * 6144;
#pragma unroll
    for (int rr = 0; rr < 8; ++rr) rv[rr] = *(const uint2*)(p + (size_t)rr * 6144);
  };
  auto writeV = [&](int buf) {
#pragma unroll
    for (int c = 0; c < 4; ++c) {
      const int d = colg * 4 + c;
      unsigned out[4];
#pragma unroll
      for (int p = 0; p < 4; ++p) {
        unsigned ua = ((const unsigned*)&rv[2 * p])[c >> 1];
        unsigned ub = ((const unsigned*)&rv[2 * p + 1])[c >> 1];
        unsigned lo = (c & 1) ? (ua >> 16) : (ua & 0xffffu);
        unsigned hi = (c & 1) ? (ub >> 16) : (ub & 0xffffu);
        out[p] = lo | (hi << 16);
      }
      *(uint4*)&VTs[buf][d][(rowg ^ (d & 7)) << 3] = *(uint4*)out;
    }
  };

  floatx4 o[8] = {};
  float m_i[4] = {-__builtin_inff(), -__builtin_inff(), -__builtin_inff(),
                  -__builtin_inff()};
  float l_i[4] = {0.f, 0.f, 0.f, 0.f};

  // ---- prologue: stage tile 0 ----
  stageK(0, 0);
  loadV(0);
  VMCNT0();
  writeV(0);
  __syncthreads();

  for (int kt = 0; kt <= qt; ++kt) {
    const int qb = kt & 1;
    const bool more = (kt < qt);
    if (more) { stageK(qb ^ 1, kt + 1); loadV(kt + 1); }

    // S = Q K^T : wave w -> 16x64 strip
    floatx4 s[4] = {};
    __builtin_amdgcn_s_setprio(1);
#pragma unroll
    for (int kc = 0; kc < 4; ++kc) {
#pragma unroll
      for (int nt = 0; nt < 4; ++nt) {
        const int row = nt * 16 + cl;
        const int c = kc * 4 + quad;
        const int sc = (c & 8) | ((c & 7) ^ (row & 7));
        bf16x8 bk = *(const bf16x8*)(&Ks[qb][row][sc * 8]);
        s[nt] = __builtin_amdgcn_mfma_f32_16x16x32_bf16(aq[kc], bk, s[nt], 0, 0, 0);
      }
    }
    __builtin_amdgcn_s_setprio(0);
    if (kt == qt) {  // causal mask on diagonal tile
#pragma unroll
      for (int nt = 0; nt < 4; ++nt)
#pragma unroll
        for (int r = 0; r < 4; ++r) {
          int qrow_l = w * 16 + quad * 4 + r;
          int kcol_l = nt * 16 + cl;
          if (kcol_l > qrow_l) s[nt][r] = -__builtin_inff();
        }
    }
    // online softmax (exp2 domain)
#pragma unroll
    for (int r = 0; r < 4; ++r) {
      float mx = fmaxf(fmaxf(s[0][r], s[1][r]), fmaxf(s[2][r], s[3][r]));
      mx = fmaxf(mx, __shfl_xor(mx, 1));
      mx = fmaxf(mx, __shfl_xor(mx, 2));
      mx = fmaxf(mx, __shfl_xor(mx, 4));
      mx = fmaxf(mx, __shfl_xor(mx, 8));
      float mn = fmaxf(m_i[r], mx);
      float a = exp2f(m_i[r] - mn);
      float rs = 0.f;
#pragma unroll
      for (int nt = 0; nt < 4; ++nt) {
        float p = exp2f(s[nt][r] - mn);
        s[nt][r] = p;
        rs += p;
      }
      rs += __shfl_xor(rs, 1);
      rs += __shfl_xor(rs, 2);
      rs += __shfl_xor(rs, 4);
      rs += __shfl_xor(rs, 8);
      l_i[r] = l_i[r] * a + rs;
      m_i[r] = mn;
#pragma unroll
      for (int nt2 = 0; nt2 < 8; ++nt2) o[nt2][r] *= a;
#pragma unroll
      for (int nt = 0; nt < 4; ++nt)
        Ps[w][quad * 4 + r][nt * 16 + cl] = f2bf(s[nt][r]);
    }
    // (no barrier: Ps[w] is same-wave; lgkmcnt orders write->read)

    // O += P V  (B operand from swizzled VTs)
    __builtin_amdgcn_s_setprio(1);
#pragma unroll
    for (int kc2 = 0; kc2 < 2; ++kc2) {
      bf16x8 ap = *(const bf16x8*)(&Ps[w][cl][kc2 * 32 + quad * 8]);
#pragma unroll
      for (int nt2 = 0; nt2 < 8; ++nt2) {
        bf16x8 bv = *(const bf16x8*)(
            &VTs[qb][nt2 * 16 + cl][((kc2 * 4 + quad) ^ (cl & 7)) << 3]);
        o[nt2] = __builtin_amdgcn_mfma_f32_16x16x32_bf16(ap, bv, o[nt2], 0, 0, 0);
      }
    }
    __builtin_amdgcn_s_setprio(0);

    if (more) {
      VMCNT0();          // K(kt+1) landed in LDS, V regs ready
      writeV(qb ^ 1);
    }
    __syncthreads();     // VTs/Ks writes visible; everyone done with buf qb
  }

  // epilogue: y[bt][h*128+d] = o/l
#pragma unroll
  for (int r = 0; r < 4; ++r) {
    float inv = 1.0f / l_i[r];
    size_t row =
        (size_t)(b * 512 + qt * 64 + w * 16 + quad * 4 + r) * 2048 + h * 128;
#pragma unroll
    for (int nt2 = 0; nt2 < 8; ++nt2)
      y[row + nt2 * 16 + cl] = f2bf(o[nt2][r] * inv);
  }
}

// ---------------------------------------------------------------------------
extern "C" void kernel_launch(void* const* d_in, const int* in_sizes, int n_in,
                              void* d_out, int out_size, void* d_ws,
                              size_t ws_size, hipStream_t stream) {
  const float* x = (const float*)d_in[0];
  const float* wqkv = (const float*)d_in[1];
  const float* wout = (const float*)d_in[2];
  float* out = (float*)d_out;

  char* ws = (char*)d_ws;
  float* cost = (float*)ws;            ws += (size_t)512 * 32 * 4;
  float* sint = (float*)ws;            ws += (size_t)512 * 32 * 4;
  unsigned short* xb = (unsigned short*)ws;    ws += (size_t)16384 * 2048 * 2;
  unsigned short* wqkvb = (unsigned short*)ws; ws += (size_t)6144 * 2048 * 2;
  unsigned short* woutb = (unsigned short*)ws; ws += (size_t)2048 * 2048 * 2;
  unsigned short* qkvb = (unsigned short*)ws;  ws += (size_t)16384 * 6144 * 2;
  unsigned short* yb = (unsigned short*)ws;    ws += (size_t)16384 * 2048 * 2;

  rope_tables<<<dim3(64), dim3(256), 0, stream>>>(cost, sint);
  cast_bf16<<<dim3(16384), dim3(256), 0, stream>>>(x, xb, 33554432 / 8);
  cast_bf16<<<dim3(6144), dim3(256), 0, stream>>>(wqkv, wqkvb, 12582912 / 8);
  cast_bf16<<<dim3(2048), dim3(256), 0, stream>>>(wout, woutb, 4194304 / 8);
  gemm256<1><<<dim3(24, 64), dim3(512), 0, stream>>>(xb, wqkvb, (void*)qkvb,
                                                     16384, 6144, 2048);
  rope_apply<<<dim3(1024), dim3(256), 0, stream>>>(qkvb, cost, sint);
  attn_kernel<<<dim3(512, 8), dim3(256), 0, stream>>>(qkvb, yb);
  gemm256<0><<<dim3(8, 64), dim3(512), 0, stream>>>(yb, woutb, (void*)out,
                                                    16384, 2048, 2048);
}

// Round 5
// 986.244 us; speedup vs baseline: 1.0418x; 1.0418x over previous
//
#include <hip/hip_runtime.h>

// ---------------------------------------------------------------------------
// FullMHA: x(32,512,2048) fp32, w_qkv(6144,2048), w_out(2048,2048)
// qkv = x @ w_qkv^T ; RoPE(64) on q,k ; causal softmax(QK^T/sqrt(128))V ;
// out = y @ w_out^T.  All GEMMs in bf16 MFMA (16x16x32), fp32 accumulate.
// R7: attention re-done for OCCUPANCY + AMORTIZATION (R6 post-mortem: 2
// waves/SIMD -> ~85% latency stall; barrier/prefetch fixes were irrelevant).
//   - 128-row q-tiles, 8 waves/block (512 thr), grid (512,4): halves
//     block-iterations (36->20 per bh) and K/V traffic; doubles compute
//     per staged tile.
//   - LDS 66KB (Ks dbuf 32K + single VTs 16K + Ps 18K) -> 2 blocks/CU
//     = 16 waves/CU = 4 waves/SIMD (2x R6 TLP). launch_bounds(512,4).
//   - 2 uniform barriers/iter (single VTs); K/V prefetch issued at iter
//     top, drained by barrier's implicit vmcnt(0) a full iter later.
//   - causal: waves fully below a k-tile skip compute (wave-uniform).
// GEMMs and rope_apply frozen from R4/R5.
// ---------------------------------------------------------------------------

typedef __bf16 bf16x8 __attribute__((ext_vector_type(8)));
typedef float floatx4 __attribute__((ext_vector_type(4)));

__device__ __forceinline__ unsigned short f2bf(float f) {
  union { float f; unsigned u; } v; v.f = f;
  unsigned r = v.u + 0x7FFFu + ((v.u >> 16) & 1u);   // RNE
  return (unsigned short)(r >> 16);
}
__device__ __forceinline__ float bf2f(unsigned short h) {
  union { unsigned u; float f; } v; v.u = ((unsigned)h) << 16; return v.f;
}

__device__ __forceinline__ void load_lds16(const void* g, void* l) {
  __builtin_amdgcn_global_load_lds((__attribute__((address_space(1))) void*)g,
                                   (__attribute__((address_space(3))) void*)l,
                                   16, 0, 0);
}

#define BARRIER() asm volatile("s_barrier" ::: "memory")
#define VMCNT6()  asm volatile("s_waitcnt vmcnt(6)" ::: "memory")
#define VMCNT0()  asm volatile("s_waitcnt vmcnt(0)" ::: "memory")

// ---------------- RoPE tables ----------------------------------------------
__global__ void rope_tables(float* __restrict__ cost, float* __restrict__ sint) {
  int i = blockIdx.x * 256 + threadIdx.x;
  if (i >= 512 * 32) return;
  int t = i >> 5, f = i & 31;
  float e = -(float)(2 * f) / 64.0f;
  float freq = powf(10000.0f, e);
  float ang = (float)t * freq;
  cost[i] = cosf(ang);
  sint[i] = sinf(ang);
}

// ---------------- fp32 -> bf16 cast, 8 elems/thread ------------------------
__global__ void cast_bf16(const float* __restrict__ in,
                          unsigned short* __restrict__ out, int n8) {
  int i = blockIdx.x * 256 + threadIdx.x;
  if (i >= n8) return;
  float4 a = ((const float4*)in)[2 * i];
  float4 b = ((const float4*)in)[2 * i + 1];
  union { uint4 v; unsigned short u[8]; } o;
  o.u[0] = f2bf(a.x); o.u[1] = f2bf(a.y); o.u[2] = f2bf(a.z); o.u[3] = f2bf(a.w);
  o.u[4] = f2bf(b.x); o.u[5] = f2bf(b.y); o.u[6] = f2bf(b.z); o.u[7] = f2bf(b.w);
  ((uint4*)out)[i] = o.v;
}

// ---------------- RoPE applied in-place to q,k of qkvb ---------------------
__global__ __launch_bounds__(256) void rope_apply(
    unsigned short* __restrict__ qkv, const float* __restrict__ cost,
    const float* __restrict__ sint) {
  const int idx = blockIdx.x * 256 + threadIdx.x;   // 262144 total
  const int tok = idx >> 4, h = idx & 15;
  const int t = tok & 511;
  const float scale = 0.08838834764831845f * 1.4426950408889634f;
  unsigned short* qrow = qkv + (size_t)tok * 6144 + h * 128;
  unsigned short* krow = qrow + 2048;

  float cs[32], sn[32];
#pragma unroll
  for (int j = 0; j < 8; ++j) {
    *(float4*)&cs[j * 4] = *(const float4*)&cost[t * 32 + j * 4];
    *(float4*)&sn[j * 4] = *(const float4*)&sint[t * 32 + j * 4];
  }
  union u32x4 { uint4 v[4]; unsigned short u[32]; };
  u32x4 q1, q2, k1, k2, o1, o2, o3, o4;
#pragma unroll
  for (int j = 0; j < 4; ++j) {
    q1.v[j] = *(const uint4*)(qrow + j * 8);
    q2.v[j] = *(const uint4*)(qrow + 32 + j * 8);
    k1.v[j] = *(const uint4*)(krow + j * 8);
    k2.v[j] = *(const uint4*)(krow + 32 + j * 8);
  }
#pragma unroll
  for (int d = 0; d < 32; ++d) {
    float c = cs[d], s = sn[d];
    float qx1 = bf2f(q1.u[d]), qx2 = bf2f(q2.u[d]);
    o1.u[d] = f2bf((qx1 * c - qx2 * s) * scale);
    o2.u[d] = f2bf((qx2 * c + qx1 * s) * scale);
    float kx1 = bf2f(k1.u[d]), kx2 = bf2f(k2.u[d]);
    o3.u[d] = f2bf(kx1 * c - kx2 * s);
    o4.u[d] = f2bf(kx2 * c + kx1 * s);
  }
#pragma unroll
  for (int j = 0; j < 4; ++j) {
    *(uint4*)(qrow + j * 8)      = o1.v[j];
    *(uint4*)(qrow + 32 + j * 8) = o2.v[j];
    *(uint4*)(krow + j * 8)      = o3.v[j];
    *(uint4*)(krow + 32 + j * 8) = o4.v[j];
  }
#pragma unroll
  for (int j = 0; j < 8; ++j) {   // q pass-through dims * scale
    union { uint4 v; unsigned short u[8]; } p, po;
    p.v = *(const uint4*)(qrow + 64 + j * 8);
#pragma unroll
    for (int jj = 0; jj < 8; ++jj) po.u[jj] = f2bf(bf2f(p.u[jj]) * scale);
    *(uint4*)(qrow + 64 + j * 8) = po.v;
  }
}

// ---------------- GEMM: C[M,N] = A[M,K] * Bt[N,K]^T  (bf16, 256^2 8-wave) --
// (Frozen R4: 4 phases/K-tile, reads 12/8/4/0, vmcnt(6) per tile.)
template <int OUT_BF16>
__global__ __launch_bounds__(512, 2) void gemm256(
    const unsigned short* __restrict__ A, const unsigned short* __restrict__ Bt,
    void* __restrict__ Cout, int M, int N, int K) {
  __shared__ __align__(16) unsigned short As[2][16384];
  __shared__ __align__(16) unsigned short Bs[2][16384];

  const int tid = threadIdx.x;
  const int nbx = gridDim.x;
  const int nwg = nbx * gridDim.y;
  const int lin = blockIdx.y * nbx + blockIdx.x;
  const int swz = (lin & 7) * (nwg >> 3) + (lin >> 3);
  const int bm = swz / nbx, bn = swz % nbx;

  const int w = tid >> 6, l = tid & 63;
  const int wm = w >> 2, wn = w & 3;
  const int quad = l >> 4, cl = l & 15;
  const int xs0 = ((0 + quad) ^ (cl & 7)) << 3;
  const int xs1 = ((4 + quad) ^ (cl & 7)) << 3;
  const int aoff = (wm * 128 + cl) * 64;
  const int boff = (wn * 64 + cl) * 64;

  const int srow = tid >> 3;
  const int lc = (tid & 7) ^ (srow & 7);
  const unsigned short* Ag = A + (size_t)(bm * 256 + srow) * K + lc * 8;
  const unsigned short* Bg = Bt + (size_t)(bn * 256 + srow) * K + lc * 8;

  auto stageA = [&](int q, int h, int k0) {
    const unsigned short* src = Ag + (size_t)(h * 128) * K + k0;
    unsigned short* dst = &As[q][0] + h * 8192 + tid * 8;
    load_lds16(src, dst);
    load_lds16(src + (size_t)64 * K, dst + 4096);
  };
  auto stageB = [&](int q, int h, int k0) {
    const unsigned short* src = Bg + (size_t)(h * 128) * K + k0;
    unsigned short* dst = &Bs[q][0] + h * 8192 + tid * 8;
    load_lds16(src, dst);
    load_lds16(src + (size_t)64 * K, dst + 4096);
  };

  floatx4 acc[8][4] = {};
  const int NT = K >> 6;

  stageA(0, 0, 0);  stageA(0, 1, 0);  stageB(0, 0, 0);  stageB(0, 1, 0);
  stageA(1, 0, 64); stageA(1, 1, 64); stageB(1, 0, 64);
  VMCNT6();
  BARRIER();

  for (int t = 0; t < NT; ++t) {
    const int q = t & 1;
    const unsigned short* pA = &As[q][0] + aoff;
    const unsigned short* pB = &Bs[q][0] + boff;
    const int k2 = (t + 2) << 6;
    const bool s2 = (t + 2) < NT;

    bf16x8 a0[4][2], a1[4][2], b0[2][2], b1[2][2];
    // phase 1: (m0, n0)
#pragma unroll
    for (int mi = 0; mi < 4; ++mi) {
      a0[mi][0] = *(const bf16x8*)(pA + mi * 1024 + xs0);
      a0[mi][1] = *(const bf16x8*)(pA + mi * 1024 + xs1);
    }
#pragma unroll
    for (int ni = 0; ni < 2; ++ni) {
      b0[ni][0] = *(const bf16x8*)(pB + ni * 1024 + xs0);
      b0[ni][1] = *(const bf16x8*)(pB + ni * 1024 + xs1);
    }
    if (t + 1 < NT) stageB(q ^ 1, 1, (t + 1) << 6);
    BARRIER();
    __builtin_amdgcn_s_setprio(1);
#pragma unroll
    for (int mi = 0; mi < 4; ++mi)
#pragma unroll
      for (int ni = 0; ni < 2; ++ni)
#pragma unroll
        for (int ks = 0; ks < 2; ++ks)
          acc[mi][ni] = __builtin_amdgcn_mfma_f32_16x16x32_bf16(
              a0[mi][ks], b0[ni][ks], acc[mi][ni], 0, 0, 0);
    __builtin_amdgcn_s_setprio(0);
    BARRIER();
    // phase 2: (m1, n0)
#pragma unroll
    for (int mi = 0; mi < 4; ++mi) {
      a1[mi][0] = *(const bf16x8*)(pA + (mi + 4) * 1024 + xs0);
      a1[mi][1] = *(const bf16x8*)(pA + (mi + 4) * 1024 + xs1);
    }
    BARRIER();
    __builtin_amdgcn_s_setprio(1);
#pragma unroll
    for (int mi = 0; mi < 4; ++mi)
#pragma unroll
      for (int ni = 0; ni < 2; ++ni)
#pragma unroll
        for (int ks = 0; ks < 2; ++ks)
          acc[mi + 4][ni] = __builtin_amdgcn_mfma_f32_16x16x32_bf16(
              a1[mi][ks], b0[ni][ks], acc[mi + 4][ni], 0, 0, 0);
    __builtin_amdgcn_s_setprio(0);
    BARRIER();
    // phase 3: (m1, n1)
#pragma unroll
    for (int ni = 0; ni < 2; ++ni) {
      b1[ni][0] = *(const bf16x8*)(pB + (ni + 2) * 1024 + xs0);
      b1[ni][1] = *(const bf16x8*)(pB + (ni + 2) * 1024 + xs1);
    }
    if (s2) stageA(q, 0, k2);
    BARRIER();
    __builtin_amdgcn_s_setprio(1);
#pragma unroll
    for (int mi = 0; mi < 4; ++mi)
#pragma unroll
      for (int ni = 0; ni < 2; ++ni)
#pragma unroll
        for (int ks = 0; ks < 2; ++ks)
          acc[mi + 4][ni + 2] = __builtin_amdgcn_mfma_f32_16x16x32_bf16(
              a1[mi][ks], b1[ni][ks], acc[mi + 4][ni + 2], 0, 0, 0);
    __builtin_amdgcn_s_setprio(0);
    BARRIER();
    // phase 4: (m0, n1)
    if (s2) { stageA(q, 1, k2); stageB(q, 0, k2); }
    BARRIER();
    __builtin_amdgcn_s_setprio(1);
#pragma unroll
    for (int mi = 0; mi < 4; ++mi)
#pragma unroll
      for (int ni = 0; ni < 2; ++ni)
#pragma unroll
        for (int ks = 0; ks < 2; ++ks)
          acc[mi][ni + 2] = __builtin_amdgcn_mfma_f32_16x16x32_bf16(
              a0[mi][ks], b1[ni][ks], acc[mi][ni + 2], 0, 0, 0);
    __builtin_amdgcn_s_setprio(0);
    if (t < NT - 2) { VMCNT6(); } else { VMCNT0(); }
    BARRIER();
  }

#pragma unroll
  for (int mi = 0; mi < 8; ++mi)
#pragma unroll
    for (int ni = 0; ni < 4; ++ni)
#pragma unroll
      for (int r = 0; r < 4; ++r) {
        const int gm = bm * 256 + wm * 128 + mi * 16 + quad * 4 + r;
        const int gn = bn * 256 + wn * 64 + ni * 16 + cl;
        const float v = acc[mi][ni][r];
        if (OUT_BF16)
          ((unsigned short*)Cout)[(size_t)gm * N + gn] = f2bf(v);
        else
          ((float*)Cout)[(size_t)gm * N + gn] = v;
      }
}

// ---------------- Causal flash attention (q,k pre-roped/scaled) ------------
// grid (B*H=512, T/128=4), 512 threads = 8 waves, wave w owns q-rows
// qt*128 + w*16 .. +16.  Q in registers; K double-buffered in LDS via
// global_load_lds (chunk-XOR swizzle); V^T single LDS buffer, next tile
// prefetched to regs at iter top, written after the post-PV barrier.
// 2 uniform barriers/iter. LDS 66KB -> 2 blocks/CU = 4 waves/SIMD.
__global__ __launch_bounds__(512, 4) void attn_kernel(
    const unsigned short* __restrict__ qkv, unsigned short* __restrict__ y) {
  __shared__ __align__(16) unsigned short Ks[2][64][128];   // chunk-swizzled
  __shared__ __align__(16) unsigned short VTs[128][64];     // chunk-swizzled
  __shared__ __align__(16) unsigned short Ps[8][16][72];

  const int bh = blockIdx.x, qt = blockIdx.y;   // qt: 128-row q tile, 0..3
  const int b = bh >> 4, h = bh & 15;
  const int tid = threadIdx.x, w = tid >> 6, l = tid & 63;
  const int quad = l >> 4, cl = l & 15;
  const int qbase = qt * 128 + w * 16;          // wave's first q row

  // ---- Q fragments -> registers (already roped & scaled) ----
  bf16x8 aq[4];
  {
    const unsigned short* qrow =
        qkv + (size_t)(b * 512 + qbase + cl) * 6144 + h * 128 + quad * 8;
#pragma unroll
    for (int kc = 0; kc < 4; ++kc) aq[kc] = *(const bf16x8*)(qrow + kc * 32);
  }

  // ---- K staging map (global_load_lds, pre-swizzled source chunk) ----
  const int srow = tid >> 4;                    // 0..31
  const int slot = tid & 15;                    // dest chunk slot
  const int kchunk = (slot & 8) | ((slot & 7) ^ (srow & 7));
  const unsigned short* kgbase =
      qkv + (size_t)(b * 512) * 6144 + 2048 + h * 128 + kchunk * 8;
  auto stageK = [&](int buf, int kt) {
#pragma unroll
    for (int slab = 0; slab < 2; ++slab) {
      const unsigned short* src =
          kgbase + (size_t)(kt * 64 + slab * 32 + srow) * 6144;
      load_lds16(src, &Ks[buf][0][0] + slab * 4096 + tid * 8);
    }
  };

  // ---- V staging: 4 kk-rows x 4 d-cols per thread, reg-transpose ----
  const int rowg = tid >> 5;        // 0..15, kk0 = rowg*4
  const int colg = tid & 31;        // d0 = colg*4
  const unsigned short* vgbase =
      qkv + (size_t)(b * 512 + rowg * 4) * 6144 + 4096 + h * 128 + colg * 4;
  uint2 rv[4];
  auto loadV = [&](int kt) {
    const unsigned short* p = vgbase + (size_t)(kt * 64) * 6144;
#pragma unroll
    for (int rr = 0; rr < 4; ++rr)
      rv[rr] = *(const uint2*)(p + (size_t)rr * 6144);
  };
  auto writeV = [&]() {
#pragma unroll
    for (int c = 0; c < 4; ++c) {
      const int d = colg * 4 + c;
      unsigned a0 = ((const unsigned*)&rv[0])[c >> 1];
      unsigned a1 = ((const unsigned*)&rv[1])[c >> 1];
      unsigned a2 = ((const unsigned*)&rv[2])[c >> 1];
      unsigned a3 = ((const unsigned*)&rv[3])[c >> 1];
      unsigned l0 = (c & 1) ? (a0 >> 16) : (a0 & 0xffffu);
      unsigned l1 = (c & 1) ? (a1 >> 16) : (a1 & 0xffffu);
      unsigned l2 = (c & 1) ? (a2 >> 16) : (a2 & 0xffffu);
      unsigned l3 = (c & 1) ? (a3 >> 16) : (a3 & 0xffffu);
      uint2 val;
      val.x = l0 | (l1 << 16);
      val.y = l2 | (l3 << 16);
      // chunk (16B) index kk0/8 = rowg>>1, half = rowg&1; slot XOR-swizzled
      *(uint2*)&VTs[d][(((rowg >> 1) ^ (d & 7)) << 3) + (rowg & 1) * 4] = val;
    }
  };

  floatx4 o[8] = {};
  float m_i[4] = {-__builtin_inff(), -__builtin_inff(), -__builtin_inff(),
                  -__builtin_inff()};
  float l_i[4] = {0.f, 0.f, 0.f, 0.f};

  const int KT = 2 * qt + 2;   // k-tiles 0..KT-1 cover cols 0..128*qt+127

  // ---- prologue: tile 0 into Ks[0] and VTs ----
  stageK(0, 0);
  loadV(0);
  __syncthreads();   // implicit vmcnt(0): Ks[0] landed; rv ready via dep
  writeV();
  __syncthreads();   // VTs(0) visible

  for (int kt = 0; kt < KT; ++kt) {
    const int qb = kt & 1;
    const bool more = (kt + 1 < KT);
    if (more) { stageK(qb ^ 1, kt + 1); loadV(kt + 1); }   // async prefetch

    const bool active = (kt * 64 <= qbase);   // wave attends this k-tile?
    if (active) {
      // S = Q K^T : 16x64 strip
      floatx4 s[4] = {};
      __builtin_amdgcn_s_setprio(1);
#pragma unroll
      for (int kc = 0; kc < 4; ++kc) {
#pragma unroll
        for (int nt = 0; nt < 4; ++nt) {
          const int row = nt * 16 + cl;
          const int c = kc * 4 + quad;
          const int sc = (c & 8) | ((c & 7) ^ (row & 7));
          bf16x8 bk = *(const bf16x8*)(&Ks[qb][row][sc * 8]);
          s[nt] =
              __builtin_amdgcn_mfma_f32_16x16x32_bf16(aq[kc], bk, s[nt], 0, 0, 0);
        }
      }
      __builtin_amdgcn_s_setprio(0);
      if (qbase < kt * 64 + 64) {   // diagonal tile for this wave
#pragma unroll
        for (int nt = 0; nt < 4; ++nt)
#pragma unroll
          for (int r = 0; r < 4; ++r) {
            int qrow_g = qbase + quad * 4 + r;
            int kcol_g = kt * 64 + nt * 16 + cl;
            if (kcol_g > qrow_g) s[nt][r] = -__builtin_inff();
          }
      }
      // online softmax (exp2 domain)
#pragma unroll
      for (int r = 0; r < 4; ++r) {
        float mx = fmaxf(fmaxf(s[0][r], s[1][r]), fmaxf(s[2][r], s[3][r]));
        mx = fmaxf(mx, __shfl_xor(mx, 1));
        mx = fmaxf(mx, __shfl_xor(mx, 2));
        mx = fmaxf(mx, __shfl_xor(mx, 4));
        mx = fmaxf(mx, __shfl_xor(mx, 8));
        float mn = fmaxf(m_i[r], mx);
        float a = exp2f(m_i[r] - mn);
        float rs = 0.f;
#pragma unroll
        for (int nt = 0; nt < 4; ++nt) {
          float p = exp2f(s[nt][r] - mn);
          s[nt][r] = p;
          rs += p;
        }
        rs += __shfl_xor(rs, 1);
        rs += __shfl_xor(rs, 2);
        rs += __shfl_xor(rs, 4);
        rs += __shfl_xor(rs, 8);
        l_i[r] = l_i[r] * a + rs;
        m_i[r] = mn;
#pragma unroll
        for (int nt2 = 0; nt2 < 8; ++nt2) o[nt2][r] *= a;
#pragma unroll
        for (int nt = 0; nt < 4; ++nt)
          Ps[w][quad * 4 + r][nt * 16 + cl] = f2bf(s[nt][r]);
      }
      // (no barrier: Ps[w] is same-wave; lgkmcnt orders write->read)

      // O += P V  (B operand from swizzled VTs, holds tile kt)
      __builtin_amdgcn_s_setprio(1);
#pragma unroll
      for (int kc2 = 0; kc2 < 2; ++kc2) {
        bf16x8 ap = *(const bf16x8*)(&Ps[w][cl][kc2 * 32 + quad * 8]);
#pragma unroll
        for (int nt2 = 0; nt2 < 8; ++nt2) {
          bf16x8 bv = *(const bf16x8*)(
              &VTs[nt2 * 16 + cl][((kc2 * 4 + quad) ^ (cl & 7)) << 3]);
          o[nt2] =
              __builtin_amdgcn_mfma_f32_16x16x32_bf16(ap, bv, o[nt2], 0, 0, 0);
        }
      }
      __builtin_amdgcn_s_setprio(0);
    }

    if (more) {          // uniform across block
      __syncthreads();   // all VTs/Ks[qb] reads done; prefetch drained
      writeV();          // VTs <- tile kt+1
      __syncthreads();   // VTs(kt+1) + Ks[qb^1] visible to all
    }
  }

  // epilogue: y[bt][h*128+d] = o/l
#pragma unroll
  for (int r = 0; r < 4; ++r) {
    float inv = 1.0f / l_i[r];
    size_t row =
        (size_t)(b * 512 + qbase + quad * 4 + r) * 2048 + h * 128;
#pragma unroll
    for (int nt2 = 0; nt2 < 8; ++nt2)
      y[row + nt2 * 16 + cl] = f2bf(o[nt2][r] * inv);
  }
}

// ---------------------------------------------------------------------------
extern "C" void kernel_launch(void* const* d_in, const int* in_sizes, int n_in,
                              void* d_out, int out_size, void* d_ws,
                              size_t ws_size, hipStream_t stream) {
  const float* x = (const float*)d_in[0];
  const float* wqkv = (const float*)d_in[1];
  const float* wout = (const float*)d_in[2];
  float* out = (float*)d_out;

  char* ws = (char*)d_ws;
  float* cost = (float*)ws;            ws += (size_t)512 * 32 * 4;
  float* sint = (float*)ws;            ws += (size_t)512 * 32 * 4;
  unsigned short* xb = (unsigned short*)ws;    ws += (size_t)16384 * 2048 * 2;
  unsigned short* wqkvb = (unsigned short*)ws; ws += (size_t)6144 * 2048 * 2;
  unsigned short* woutb = (unsigned short*)ws; ws += (size_t)2048 * 2048 * 2;
  unsigned short* qkvb = (unsigned short*)ws;  ws += (size_t)16384 * 6144 * 2;
  unsigned short* yb = (unsigned short*)ws;    ws += (size_t)16384 * 2048 * 2;

  rope_tables<<<dim3(64), dim3(256), 0, stream>>>(cost, sint);
  cast_bf16<<<dim3(16384), dim3(256), 0, stream>>>(x, xb, 33554432 / 8);
  cast_bf16<<<dim3(6144), dim3(256), 0, stream>>>(wqkv, wqkvb, 12582912 / 8);
  cast_bf16<<<dim3(2048), dim3(256), 0, stream>>>(wout, woutb, 4194304 / 8);
  gemm256<1><<<dim3(24, 64), dim3(512), 0, stream>>>(xb, wqkvb, (void*)qkvb,
                                                     16384, 6144, 2048);
  rope_apply<<<dim3(1024), dim3(256), 0, stream>>>(qkvb, cost, sint);
  attn_kernel<<<dim3(512, 4), dim3(512), 0, stream>>>(qkvb, yb);
  gemm256<0><<<dim3(8, 64), dim3(512), 0, stream>>>(yb, woutb, (void*)out,
                                                    16384, 2048, 2048);
}